// Round 17
// baseline (237.455 us; speedup 1.0000x reference)
//
#include <hip/hip_runtime.h>

#define DD 64
#define RR 12
#define KTOT 832   // 768 (A·Wrel) + 64 (h·(Wself+Wskip))
#define NKS 26     // 832 / 32 k-steps
#define ASTR 840   // LDS A row stride in halfs (420 words ≡ 4 mod 32: even banks)
#define TROWS 16   // nodes per block tile — proven geometry, do not change
#define WZE_CAP 512 // per-block prefetched edge-weight capacity (4 KB LDS)
#define EPB2 8192  // edges per block in bucket passes

typedef _Float16 half8v __attribute__((ext_vector_type(8)));
typedef __attribute__((ext_vector_type(4))) float f32x4;

// layer-1 EW table straight from x (h0 row is a function of scalar x[n]):
// EW[n*12+r] = (ev, ev*gate)
__global__ void k_sgw2(const float* __restrict__ x, const float* __restrict__ Wemb,
                       const float* __restrict__ bemb,
                       const float* __restrict__ q, const float* __restrict__ g,
                       const float* __restrict__ gb, float2* __restrict__ EW, int N) {
    __shared__ float We[DD], Be[DD], qs[RR * 65], gs[RR * 65];
    int tid = threadIdx.x;
    if (tid < DD) { We[tid] = Wemb[tid]; Be[tid] = bemb[tid]; }
    for (int i = tid; i < RR * DD; i += 256) {
        int r = i >> 6, c = i & 63;
        qs[r * 65 + c] = q[i];
        gs[r * 65 + c] = g[i];
    }
    __syncthreads();
    int t = blockIdx.x * 256 + tid;
    if (t >= N * RR) return;
    int n = t / RR, r = t - n * RR;
    float xv = x[n];
    const float* qp = qs + r * 65;
    const float* gp = gs + r * 65;
    float aq = 0.f, ag = 0.f;
#pragma unroll
    for (int d = 0; d < DD; d++) {
        float h = fmaf(xv, We[d], Be[d]);
        h = h > 0.f ? h : 0.f;
        aq = fmaf(h, qp[d], aq);
        ag = fmaf(h, gp[d], ag);
    }
    float sc = aq > 0.f ? aq : 0.01f * aq;       // leaky_relu
    float ev = expf(sc);                          // softmax max-shift invariant
    float gate = 1.f / (1.f + expf(-(ag + gb[0])));
    EW[t] = make_float2(ev, ev * gate);
}

// ============ coalesced two-level counting sort by dst ============
// bucket = dst >> 7 (128 nodes per bucket). payload u32 = dlow<<20 | et<<16 | src

__global__ void k_bh(const int* __restrict__ dst, int* __restrict__ bcnt,
                     int E, int nbuck) {
    __shared__ int lh[512];
    int tid = threadIdx.x;
    for (int i = tid; i < 512; i += 512) lh[i] = 0;
    __syncthreads();
    int base = blockIdx.x * EPB2;
    int lim = base + EPB2 < E ? base + EPB2 : E;
    for (int i = base + tid; i < lim; i += 512)
        atomicAdd(&lh[dst[i] >> 7], 1);
    __syncthreads();
    for (int i = tid; i < nbuck; i += 512)
        if (lh[i]) atomicAdd(&bcnt[i], lh[i]);
}

__global__ void k_bscan(const int* __restrict__ bcnt, int* __restrict__ bbase,
                        int* __restrict__ bcur, int nbuck, int E) {
    __shared__ int wsum[8];
    int tid = threadIdx.x, lane = tid & 63, wv = tid >> 6;
    int v = (tid < nbuck) ? bcnt[tid] : 0;
    int incl = v;
#pragma unroll
    for (int d = 1; d < 64; d <<= 1) {
        int t2 = __shfl_up(incl, d);
        if (lane >= d) incl += t2;
    }
    if (lane == 63) wsum[wv] = incl;
    __syncthreads();
    int pre = 0;
#pragma unroll
    for (int w = 0; w < 8; w++) if (w < wv) pre += wsum[w];
    int excl = pre + incl - v;
    if (tid < nbuck) { bbase[tid] = excl; bcur[tid] = excl; }
    if (tid == nbuck - 1) bbase[nbuck] = excl + v;   // == E
}

__global__ void k_bscat(const int* __restrict__ src, const int* __restrict__ dst,
                        const int* __restrict__ et, int* __restrict__ bcur,
                        unsigned* __restrict__ epk2, int E, int nbuck) {
    __shared__ int lh[512];
    __shared__ int lcur[512];
    int tid = threadIdx.x;
    for (int i = tid; i < 512; i += 512) lh[i] = 0;
    __syncthreads();
    int base = blockIdx.x * EPB2;
    int lim = base + EPB2 < E ? base + EPB2 : E;
    for (int i = base + tid; i < lim; i += 512)
        atomicAdd(&lh[dst[i] >> 7], 1);
    __syncthreads();
    for (int i = tid; i < nbuck; i += 512)
        lcur[i] = lh[i] ? atomicAdd(&bcur[i], lh[i]) : 0;
    __syncthreads();
    for (int i = base + tid; i < lim; i += 512) {
        int d = dst[i];
        int pos = atomicAdd(&lcur[d >> 7], 1);
        epk2[pos] = ((unsigned)(d & 127) << 20) | ((unsigned)et[i] << 16) | (unsigned)src[i];
    }
}

__global__ void k_b2(const unsigned* __restrict__ epk2, const int* __restrict__ bbase,
                     unsigned* __restrict__ epk, int* __restrict__ offd,
                     int N, int E) {
    int b = blockIdx.x, tid = threadIdx.x;
    int p0 = bbase[b], p1 = bbase[b + 1], cb = p1 - p0;
    __shared__ int hist[128], cur[128];
    __shared__ unsigned stg[4096];
    if (tid < 128) hist[tid] = 0;
    __syncthreads();
    for (int i = tid; i < cb; i += 256)
        atomicAdd(&hist[(epk2[p0 + i] >> 20) & 127], 1);
    __syncthreads();
    if (tid == 0) {
        int a = 0;
        for (int j = 0; j < 128; j++) { int c = hist[j]; hist[j] = a; a += c; }
    }
    __syncthreads();
    if (tid < 128) {
        cur[tid] = hist[tid];
        int node = b * 128 + tid;
        if (node < N) offd[node] = p0 + hist[tid];
    }
    if (b == 0 && tid == 0) offd[N] = E;
    __syncthreads();
    if (cb <= 4096) {
        for (int i = tid; i < cb; i += 256) {
            unsigned pk = epk2[p0 + i];
            int pos = atomicAdd(&cur[(pk >> 20) & 127], 1);
            stg[pos] = pk & 0xFFFFFu;
        }
        __syncthreads();
        for (int i = tid; i < cb; i += 256) epk[p0 + i] = stg[i];
    } else {   // statistically never; correctness fallback
        for (int i = tid; i < cb; i += 256) {
            unsigned pk = epk2[p0 + i];
            int pos = atomicAdd(&cur[(pk >> 20) & 127], 1);
            epk[p0 + pos] = pk & 0xFFFFFu;
        }
    }
}

// -------- weight prep, all 3 layers in ONE launch --------
// per layer: blocks 0..25 = B fragments (fp16 hi/lo planes); 26..28 = q/g
__global__ void k_wprep3(
    const float* __restrict__ Wr0, const float* __restrict__ Ws0, const float* __restrict__ Wk0,
    const float* __restrict__ av0, const float* __restrict__ gw0,
    _Float16* __restrict__ Bh0, _Float16* __restrict__ Bl0, float* __restrict__ q0, float* __restrict__ g0,
    const float* __restrict__ Wr1, const float* __restrict__ Ws1, const float* __restrict__ Wk1,
    const float* __restrict__ av1, const float* __restrict__ gw1,
    _Float16* __restrict__ Bh1, _Float16* __restrict__ Bl1, float* __restrict__ q1, float* __restrict__ g1,
    const float* __restrict__ Wr2, const float* __restrict__ Ws2, const float* __restrict__ Wk2,
    const float* __restrict__ av2, const float* __restrict__ gw2,
    _Float16* __restrict__ Bh2, _Float16* __restrict__ Bl2, float* __restrict__ q2, float* __restrict__ g2) {
    int layer = blockIdx.x / (NKS + 3);
    int bx = blockIdx.x % (NKS + 3);
    const float* Wrel  = layer == 0 ? Wr0 : layer == 1 ? Wr1 : Wr2;
    const float* Wself = layer == 0 ? Ws0 : layer == 1 ? Ws1 : Ws2;
    const float* Wskip = layer == 0 ? Wk0 : layer == 1 ? Wk1 : Wk2;
    const float* av    = layer == 0 ? av0 : layer == 1 ? av1 : av2;
    const float* gw    = layer == 0 ? gw0 : layer == 1 ? gw1 : gw2;
    _Float16* Bh = layer == 0 ? Bh0 : layer == 1 ? Bh1 : Bh2;
    _Float16* Bl = layer == 0 ? Bl0 : layer == 1 ? Bl1 : Bl2;
    float* q = layer == 0 ? q0 : layer == 1 ? q1 : q2;
    float* g = layer == 0 ? g0 : layer == 1 ? g1 : g2;

    if (bx < NKS) {
        int t = bx * 256 + threadIdx.x;
        int ks = t >> 8, ct = (t >> 6) & 3, lane = t & 63;
        int col = ct * 16 + (lane & 15);
        int kb = ks * 32 + ((lane >> 4) << 3);
        _Float16* ph = Bh + (size_t)t * 8;
        _Float16* pl = Bl + (size_t)t * 8;
#pragma unroll
        for (int i = 0; i < 8; i++) {
            int k = kb + i;
            float v;
            if (k < 768) v = Wrel[(size_t)k * DD + col];
            else {
                v = Wself[(size_t)(k - 768) * DD + col];
                if (Wskip) v += Wskip[(size_t)(k - 768) * DD + col];
            }
            _Float16 h = (_Float16)v;
            ph[i] = h;
            pl[i] = (_Float16)(v - (float)h);
        }
    } else {
        int t = (bx - NKS) * 256 + threadIdx.x;
        if (t >= RR * DD) return;
        const float* wp = Wrel + (size_t)t * DD;
        float aq = 0.f, ag = 0.f;
#pragma unroll
        for (int e = 0; e < DD; e++) { float w = wp[e]; aq += w * av[e]; ag += w * gw[e]; }
        q[t] = aq; g[t] = ag;
    }
}

// ---------------- fused layer kernel: aggregate -> LDS A-tile -> MFMA ------
// Block prologue: since edges are dst-sorted, the block's 16 nodes own ONE
// contiguous edge range; all 512 threads cooperatively gather its (ev,
// ev*gate) pairs into a 4 KB LDS buffer (one parallel latency round-trip).
// Phase 1 then reads weights via wave-uniform LDS broadcast — the measured
// streamed-weight speed (57.7 µs) without the k_ew pass. Overflow (>512
// edges/block, P~e^-40) falls back to direct gather per node.
#define AGG_EDGE(ee, wy, hh)                                       \
    switch (ee) {                                                  \
        case 0:  acc[0]  = fmaf(wy, hh, acc[0]);  break;           \
        case 1:  acc[1]  = fmaf(wy, hh, acc[1]);  break;           \
        case 2:  acc[2]  = fmaf(wy, hh, acc[2]);  break;           \
        case 3:  acc[3]  = fmaf(wy, hh, acc[3]);  break;           \
        case 4:  acc[4]  = fmaf(wy, hh, acc[4]);  break;           \
        case 5:  acc[5]  = fmaf(wy, hh, acc[5]);  break;           \
        case 6:  acc[6]  = fmaf(wy, hh, acc[6]);  break;           \
        case 7:  acc[7]  = fmaf(wy, hh, acc[7]);  break;           \
        case 8:  acc[8]  = fmaf(wy, hh, acc[8]);  break;           \
        case 9:  acc[9]  = fmaf(wy, hh, acc[9]);  break;           \
        case 10: acc[10] = fmaf(wy, hh, acc[10]); break;           \
        default: acc[11] = fmaf(wy, hh, acc[11]); break;           \
    }

template<int NB, bool MASKED, int XD, bool WL>
__device__ __forceinline__ void ebatch(const unsigned* __restrict__ epk,
                                       const float2* __restrict__ EWr,
                                       const float2* wze, int pb0,
                                       const _Float16* __restrict__ hin16,
                                       const float* __restrict__ xsrc,
                                       float we_r, float be_r,
                                       int p, int p1, int lane,
                                       float acc[RR], float& zacc) {
    int len = p1 - p;   // uniform; >= 1 when called masked
    unsigned pk[NB];
    float2 ew[NB];
#pragma unroll
    for (int i = 0; i < NB; i++) {
        int ii = MASKED ? (i < len ? i : len - 1) : i;   // clamp: always-valid
        pk[i] = epk[p + ii];
    }
#pragma unroll
    for (int i = 0; i < NB; i++) {
        int ii = MASKED ? (i < len ? i : len - 1) : i;
        ew[i] = WL ? wze[p - pb0 + ii]   // LDS broadcast (uniform address)
                   : EWr[(size_t)(pk[i] & 0xFFFFu) * RR + ((pk[i] >> 16) & 15u)];
    }
    if (XD) {
        float xs[NB];
#pragma unroll
        for (int i = 0; i < NB; i++) xs[i] = xsrc[pk[i] & 0xFFFFu];
        __builtin_amdgcn_sched_barrier(0);
#pragma unroll
        for (int i = 0; i < NB; i++) {
            int e = __builtin_amdgcn_readfirstlane((int)((pk[i] >> 16) & 15u));
            float hh = fmaf(xs[i], we_r, be_r);
            hh = hh > 0.f ? hh : 0.f;
            float wx = ew[i].x, wy = ew[i].y;
            if (MASKED && i >= 1) {
                bool ok = i < len;
                wx = ok ? wx : 0.f;
                wy = ok ? wy : 0.f;
            }
            zacc += wx;
            AGG_EDGE(e, wy, hh);
        }
    } else {
        _Float16 hr[NB];
#pragma unroll
        for (int i = 0; i < NB; i++)
            hr[i] = hin16[(size_t)(pk[i] & 0xFFFFu) * DD + lane];
        __builtin_amdgcn_sched_barrier(0);
#pragma unroll
        for (int i = 0; i < NB; i++) {
            int e = __builtin_amdgcn_readfirstlane((int)((pk[i] >> 16) & 15u));
            float hh = (float)hr[i];
            float wx = ew[i].x, wy = ew[i].y;
            if (MASKED && i >= 1) {
                bool ok = i < len;
                wx = ok ? wx : 0.f;
                wy = ok ? wy : 0.f;
            }
            zacc += wx;
            AGG_EDGE(e, wy, hh);
        }
    }
}

template<int XD, bool WL>
__device__ __forceinline__ void node_edges(const unsigned* __restrict__ epk,
                                           const float2* __restrict__ EWr,
                                           const float2* wze, int pb0,
                                           const _Float16* __restrict__ hin16,
                                           const float* __restrict__ xsrc,
                                           float we_r, float be_r,
                                           int p0, int p1, int lane,
                                           float acc[RR], float& zacc) {
    int p = p0;
    while (p + 16 <= p1) {
        ebatch<16, false, XD, WL>(epk, EWr, wze, pb0, hin16, xsrc, we_r, be_r,
                                  p, p1, lane, acc, zacc);
        p += 16;
    }
    int rem = p1 - p;
    if (rem > 8)      ebatch<16, true, XD, WL>(epk, EWr, wze, pb0, hin16, xsrc, we_r, be_r,
                                               p, p1, lane, acc, zacc);
    else if (rem > 0) ebatch<8, true, XD, WL>(epk, EWr, wze, pb0, hin16, xsrc, we_r, be_r,
                                              p, p1, lane, acc, zacc);
}

template<int XD>
__global__ void __launch_bounds__(512, 8)
k_fused(const unsigned* __restrict__ epk, const int* __restrict__ offd,
        const _Float16* __restrict__ hin16,
        const float* __restrict__ xsrc, const float* __restrict__ Wemb,
        const float* __restrict__ bemb,
        const float2* __restrict__ EWr, float2* __restrict__ EWw,
        const _Float16* __restrict__ Bh, const _Float16* __restrict__ Bl,
        const float* __restrict__ bias, float* __restrict__ out,
        _Float16* __restrict__ hout16, int N, int act,
        const float* __restrict__ qn, const float* __restrict__ gn,
        const float* __restrict__ gbn) {
    __shared__ __align__(16) _Float16 At[TROWS * ASTR];   // 26880 B
    // ubuf union: phase 1 = wze[512] float2 (4096 B);
    // phase 2/epilogue = Hf (1088 f32) + qg (1632 f32) = 10880 B
    __shared__ __align__(16) float ubuf[2720];
    __shared__ int offs[TROWS + 1];
    __shared__ int claim;
    int tid = threadIdx.x, lane = tid & 63, w = tid >> 6;
    int nb0 = blockIdx.x * TROWS;
    if (tid == 0) claim = 0;
    if (tid < TROWS + 1) {
        int nn = nb0 + tid;
        offs[tid] = (nn <= N) ? offd[nn] : 0;
    }
    float we_r = 0.f, be_r = 0.f;
    if (XD) { we_r = Wemb[lane]; be_r = bemb[lane]; }
    __syncthreads();

    // ---- prologue: cooperative edge-weight prefetch into LDS ----
    float2* wze = (float2*)ubuf;
    int lastIdx = N - nb0; if (lastIdx > TROWS) lastIdx = TROWS;
    int pb0 = offs[0];
    int pb1 = offs[lastIdx];
    int nbe = pb1 - pb0; if (nbe > WZE_CAP) nbe = WZE_CAP;
    for (int i = tid; i < nbe; i += 512) {
        unsigned pk = epk[pb0 + i];
        wze[i] = EWr[(size_t)(pk & 0xFFFFu) * RR + ((pk >> 16) & 15u)];
    }
    __syncthreads();

    // ---- phase 1: waves claim nodes until the tile is done ----
    for (;;) {
        int t0 = 0;
        if (lane == 0) t0 = atomicAdd(&claim, 1);
        int nl = __builtin_amdgcn_readfirstlane(t0);
        if (nl >= TROWS) break;
        int node = nb0 + nl;
        _Float16* Ar = At + nl * ASTR;
        if (node >= N) {
            for (int k = lane; k < KTOT; k += 64) Ar[k] = (_Float16)0.f;
            continue;
        }
        int p0 = __builtin_amdgcn_readfirstlane(offs[nl]);
        int p1 = __builtin_amdgcn_readfirstlane(offs[nl + 1]);

        float acc[RR];
#pragma unroll
        for (int r = 0; r < RR; r++) acc[r] = 0.f;
        float zacc = 0.f;
        if (p1 - pb0 <= WZE_CAP)   // fast path: weights from LDS
            node_edges<XD, true>(epk, EWr, wze, pb0, hin16, xsrc, we_r, be_r,
                                 p0, p1, lane, acc, zacc);
        else                        // overflow: direct gather (never in practice)
            node_edges<XD, false>(epk, EWr, wze, pb0, hin16, xsrc, we_r, be_r,
                                  p0, p1, lane, acc, zacc);

        float inv = 1.f / (zacc + 1e-16f);
#pragma unroll
        for (int r = 0; r < RR; r++) Ar[r * DD + lane] = (_Float16)(acc[r] * inv);
        if (XD) {   // self/skip col recomputed from x[node]
            float h0v = fmaf(xsrc[node], we_r, be_r);
            h0v = h0v > 0.f ? h0v : 0.f;
            Ar[768 + lane] = (_Float16)h0v;
        } else {
            Ar[768 + lane] = hin16[(size_t)node * DD + lane];
        }
    }
    __syncthreads();

    float* Hf = ubuf;            // 16 rows, stride 68 (1088 floats)
    float* qg = ubuf + 1088;     // q rows [0..816), g rows [816..1632)

    // ---- phase 2: waves 0-3 MFMA; waves 4-7 stage next layer's q/g ----
    if (w < 4) {
        const half8v* Bh8 = (const half8v*)Bh;
        const half8v* Bl8 = (const half8v*)Bl;
        const _Float16* abase = At + (lane & 15) * ASTR + ((lane >> 4) << 3);
        f32x4 acc0 = {0.f, 0.f, 0.f, 0.f};
#pragma unroll 4
        for (int ks = 0; ks < NKS; ++ks) {
            half8v ah = *(const half8v*)(abase + ks * 32);
            size_t bb = (size_t)(ks * 4 + w) * 64 + lane;
            half8v bh = Bh8[bb];
            half8v bl = Bl8[bb];
            acc0 = __builtin_amdgcn_mfma_f32_16x16x32_f16(ah, bh, acc0, 0, 0, 0);
            acc0 = __builtin_amdgcn_mfma_f32_16x16x32_f16(ah, bl, acc0, 0, 0, 0);
        }

        // epilogue: D layout col=lane&15, row=(lane>>4)*4+j
        int colb = lane & 15, kg = lane >> 4;
        int c = w * 16 + colb;
        float bv = bias[c];
#pragma unroll
        for (int j = 0; j < 4; j++) {
            int rl = kg * 4 + j;
            int row = nb0 + rl;
            if (row < N) {
                float v = acc0[j] + bv;
                if (act) v = v > 0.f ? v : 0.f;
                if (out) out[(size_t)row * DD + c] = v;
                if (hout16) hout16[(size_t)row * DD + c] = (_Float16)v;
                if (EWw) Hf[rl * 68 + c] = v;
            }
        }
    } else if (EWw) {
        for (int i = tid - 256; i < RR * DD; i += 256) {
            int r = i >> 6, c = i & 63;
            qg[r * 68 + c] = qn[i];
            qg[816 + r * 68 + c] = gn[i];
        }
    }

    // ---- EW epilogue: next layer's (ev, ev*gate) from fp32 tile, all-LDS ----
    if (EWw) {
        __syncthreads();
        if (tid < TROWS * RR) {
            int nl = tid / RR, r = tid - nl * RR;
            int node = nb0 + nl;
            if (node < N) {
                const float* hp = Hf + nl * 68;
                const float* qp = qg + r * 68;
                const float* gp = qg + 816 + r * 68;
                float aq = 0.f, ag = 0.f;
#pragma unroll
                for (int c4 = 0; c4 < 16; c4++) {
                    float4 hv = *(const float4*)(hp + c4 * 4);
                    float4 qv = *(const float4*)(qp + c4 * 4);
                    float4 gv = *(const float4*)(gp + c4 * 4);
                    aq += hv.x * qv.x + hv.y * qv.y + hv.z * qv.z + hv.w * qv.w;
                    ag += hv.x * gv.x + hv.y * gv.y + hv.z * gv.z + hv.w * gv.w;
                }
                float sc = aq > 0.f ? aq : 0.01f * aq;
                float ev = expf(sc);
                float gate = 1.f / (1.f + expf(-(ag + gbn[0])));
                EWw[(size_t)node * RR + r] = make_float2(ev, ev * gate);
            }
        }
    }
}

extern "C" void kernel_launch(void* const* d_in, const int* in_sizes, int n_in,
                              void* d_out, int out_size, void* d_ws, size_t ws_size,
                              hipStream_t stream) {
    const float* x    = (const float*)d_in[0];
    const int*   src  = (const int*)d_in[1];
    const int*   dst  = (const int*)d_in[2];
    const int*   etyp = (const int*)d_in[3];
    const float* Wemb = (const float*)d_in[4];
    const float* bemb = (const float*)d_in[5];
    const int N = in_sizes[0];
    const int E = in_sizes[1];
    const int nbuck = (N + 127) >> 7;
    const int nblk2 = (E + EPB2 - 1) / EPB2;

    const float* Wrel[3];  const float* Wself[3]; const float* bb[3];
    const float* gwv[3];   const float* gbv[3];   const float* av[3];
    for (int l = 0; l < 3; l++) {
        int o = 6 + 6 * l;
        Wrel[l]  = (const float*)d_in[o + 0];
        Wself[l] = (const float*)d_in[o + 1];
        bb[l]    = (const float*)d_in[o + 2];
        gwv[l]   = (const float*)d_in[o + 3];
        gbv[l]   = (const float*)d_in[o + 4];
        av[l]    = (const float*)d_in[o + 5];
    }
    const float* Wskip[3] = { nullptr, (const float*)d_in[24], (const float*)d_in[25] };

    // ---- workspace ----
    float* p = (float*)d_ws;
    _Float16* h16A = (_Float16*)p; p += (size_t)N * DD / 2;   // fp16 copy (ping)
    _Float16* h16B = (_Float16*)p; p += (size_t)N * DD / 2;   // fp16 copy (pong)
    float2* EWa = (float2*)p; p += (size_t)N * RR * 2;        // EW ping
    float2* EWb = (float2*)p; p += (size_t)N * RR * 2;        // EW pong
    float* qv3[3]; float* gv3[3]; _Float16* Bh3[3]; _Float16* Bl3[3];
    for (int l = 0; l < 3; l++) {
        qv3[l] = p; p += RR * DD;
        gv3[l] = p; p += RR * DD;
        Bh3[l] = (_Float16*)p; p += NKS * 4 * 64 * 8 / 2;
        Bl3[l] = (_Float16*)p; p += NKS * 4 * 64 * 8 / 2;
    }
    unsigned* epk2 = (unsigned*)p; p += E;
    unsigned* epk  = (unsigned*)p; p += E;
    int* bcnt  = (int*)p; p += 512;
    int* bbase = (int*)p; p += 516;
    int* bcur  = (int*)p; p += 512;
    int* offd  = (int*)p; p += N + 4;

    const int B = 256;

    // weight prep for all 3 layers — ONE launch
    k_wprep3<<<3 * (NKS + 3), B, 0, stream>>>(
        Wrel[0], Wself[0], Wskip[0], av[0], gwv[0], Bh3[0], Bl3[0], qv3[0], gv3[0],
        Wrel[1], Wself[1], Wskip[1], av[1], gwv[1], Bh3[1], Bl3[1], qv3[1], gv3[1],
        Wrel[2], Wself[2], Wskip[2], av[2], gwv[2], Bh3[2], Bl3[2], qv3[2], gv3[2]);

    // coalesced two-level dst-sort (once; reused by all layers)
    hipMemsetAsync(bcnt, 0, 512 * 4, stream);
    k_bh<<<nblk2, 512, 0, stream>>>(dst, bcnt, E, nbuck);
    k_bscan<<<1, 512, 0, stream>>>(bcnt, bbase, bcur, nbuck, E);
    k_bscat<<<nblk2, 512, 0, stream>>>(src, dst, etyp, bcur, epk2, E, nbuck);
    k_b2<<<nbuck, 256, 0, stream>>>(epk2, bbase, epk, offd, N, E);

    // layer 1's EW straight from x
    k_sgw2<<<(N * RR + B - 1) / B, B, 0, stream>>>(x, Wemb, bemb, qv3[0], gv3[0],
                                                   gbv[0], EWa, N);

    const int fblocks = (N + TROWS - 1) / TROWS;

    // layer 1: h0 from x in-register; reads EWa, writes EWb + h16B
    k_fused<1><<<fblocks, 512, 0, stream>>>(epk, offd, nullptr, x, Wemb, bemb,
                                            EWa, EWb, Bh3[0], Bl3[0], bb[0],
                                            nullptr, h16B, N, 1,
                                            qv3[1], gv3[1], gbv[1]);
    // layer 2: in h16B; reads EWb, writes EWa + h16A
    k_fused<0><<<fblocks, 512, 0, stream>>>(epk, offd, h16B, nullptr, nullptr, nullptr,
                                            EWb, EWa, Bh3[1], Bl3[1], bb[1],
                                            nullptr, h16A, N, 1,
                                            qv3[2], gv3[2], gbv[2]);
    // layer 3: in h16A; reads EWa; out d_out f32, no act, no EW epilogue
    k_fused<0><<<fblocks, 512, 0, stream>>>(epk, offd, h16A, nullptr, nullptr, nullptr,
                                            EWa, nullptr, Bh3[2], Bl3[2], bb[2],
                                            (float*)d_out, nullptr, N, 0,
                                            nullptr, nullptr, nullptr);
}

// Round 18
// 220.492 us; speedup vs baseline: 1.0769x; 1.0769x over previous
//
#include <hip/hip_runtime.h>

#define DD 64
#define RR 12
#define KTOT 832   // 768 (A·Wrel) + 64 (h·(Wself+Wskip))
#define NKS 26     // 832 / 32 k-steps
#define ASTR 840   // LDS A row stride in halfs (420 words ≡ 4 mod 32: even banks)
#define TROWS 16   // nodes per block tile — proven geometry, do not change
#define EPB2 8192  // edges per block in bucket passes

typedef _Float16 half8v __attribute__((ext_vector_type(8)));
typedef __attribute__((ext_vector_type(4))) float f32x4;

// layer-1 EW table straight from x (h0 row is a function of scalar x[n]):
// EW[n*12+r] = (ev, ev*gate)
__global__ void k_sgw2(const float* __restrict__ x, const float* __restrict__ Wemb,
                       const float* __restrict__ bemb,
                       const float* __restrict__ q, const float* __restrict__ g,
                       const float* __restrict__ gb, float2* __restrict__ EW, int N) {
    __shared__ float We[DD], Be[DD], qs[RR * 65], gs[RR * 65];
    int tid = threadIdx.x;
    if (tid < DD) { We[tid] = Wemb[tid]; Be[tid] = bemb[tid]; }
    for (int i = tid; i < RR * DD; i += 256) {
        int r = i >> 6, c = i & 63;
        qs[r * 65 + c] = q[i];
        gs[r * 65 + c] = g[i];
    }
    __syncthreads();
    int t = blockIdx.x * 256 + tid;
    if (t >= N * RR) return;
    int n = t / RR, r = t - n * RR;
    float xv = x[n];
    const float* qp = qs + r * 65;
    const float* gp = gs + r * 65;
    float aq = 0.f, ag = 0.f;
#pragma unroll
    for (int d = 0; d < DD; d++) {
        float h = fmaf(xv, We[d], Be[d]);
        h = h > 0.f ? h : 0.f;
        aq = fmaf(h, qp[d], aq);
        ag = fmaf(h, gp[d], ag);
    }
    float sc = aq > 0.f ? aq : 0.01f * aq;       // leaky_relu
    float ev = expf(sc);                          // softmax max-shift invariant
    float gate = 1.f / (1.f + expf(-(ag + gb[0])));
    EW[t] = make_float2(ev, ev * gate);
}

// ============ coalesced two-level counting sort by dst ============
// bucket = dst >> 7 (128 nodes per bucket). payload u32 = dlow<<20 | et<<16 | src

__global__ void k_bh(const int* __restrict__ dst, int* __restrict__ bcnt,
                     int E, int nbuck) {
    __shared__ int lh[512];
    int tid = threadIdx.x;
    for (int i = tid; i < 512; i += 512) lh[i] = 0;
    __syncthreads();
    int base = blockIdx.x * EPB2;
    int lim = base + EPB2 < E ? base + EPB2 : E;
    for (int i = base + tid; i < lim; i += 512)
        atomicAdd(&lh[dst[i] >> 7], 1);
    __syncthreads();
    for (int i = tid; i < nbuck; i += 512)
        if (lh[i]) atomicAdd(&bcnt[i], lh[i]);
}

__global__ void k_bscan(const int* __restrict__ bcnt, int* __restrict__ bbase,
                        int* __restrict__ bcur, int nbuck, int E) {
    __shared__ int wsum[8];
    int tid = threadIdx.x, lane = tid & 63, wv = tid >> 6;
    int v = (tid < nbuck) ? bcnt[tid] : 0;
    int incl = v;
#pragma unroll
    for (int d = 1; d < 64; d <<= 1) {
        int t2 = __shfl_up(incl, d);
        if (lane >= d) incl += t2;
    }
    if (lane == 63) wsum[wv] = incl;
    __syncthreads();
    int pre = 0;
#pragma unroll
    for (int w = 0; w < 8; w++) if (w < wv) pre += wsum[w];
    int excl = pre + incl - v;
    if (tid < nbuck) { bbase[tid] = excl; bcur[tid] = excl; }
    if (tid == nbuck - 1) bbase[nbuck] = excl + v;   // == E
}

__global__ void k_bscat(const int* __restrict__ src, const int* __restrict__ dst,
                        const int* __restrict__ et, int* __restrict__ bcur,
                        unsigned* __restrict__ epk2, int E, int nbuck) {
    __shared__ int lh[512];
    __shared__ int lcur[512];
    int tid = threadIdx.x;
    for (int i = tid; i < 512; i += 512) lh[i] = 0;
    __syncthreads();
    int base = blockIdx.x * EPB2;
    int lim = base + EPB2 < E ? base + EPB2 : E;
    for (int i = base + tid; i < lim; i += 512)
        atomicAdd(&lh[dst[i] >> 7], 1);
    __syncthreads();
    for (int i = tid; i < nbuck; i += 512)
        lcur[i] = lh[i] ? atomicAdd(&bcur[i], lh[i]) : 0;
    __syncthreads();
    for (int i = base + tid; i < lim; i += 512) {
        int d = dst[i];
        int pos = atomicAdd(&lcur[d >> 7], 1);
        epk2[pos] = ((unsigned)(d & 127) << 20) | ((unsigned)et[i] << 16) | (unsigned)src[i];
    }
}

__global__ void k_b2(const unsigned* __restrict__ epk2, const int* __restrict__ bbase,
                     unsigned* __restrict__ epk, int* __restrict__ offd,
                     int N, int E) {
    int b = blockIdx.x, tid = threadIdx.x;
    int p0 = bbase[b], p1 = bbase[b + 1], cb = p1 - p0;
    __shared__ int hist[128], cur[128];
    __shared__ unsigned stg[4096];
    if (tid < 128) hist[tid] = 0;
    __syncthreads();
    for (int i = tid; i < cb; i += 256)
        atomicAdd(&hist[(epk2[p0 + i] >> 20) & 127], 1);
    __syncthreads();
    if (tid == 0) {
        int a = 0;
        for (int j = 0; j < 128; j++) { int c = hist[j]; hist[j] = a; a += c; }
    }
    __syncthreads();
    if (tid < 128) {
        cur[tid] = hist[tid];
        int node = b * 128 + tid;
        if (node < N) offd[node] = p0 + hist[tid];
    }
    if (b == 0 && tid == 0) offd[N] = E;
    __syncthreads();
    if (cb <= 4096) {
        for (int i = tid; i < cb; i += 256) {
            unsigned pk = epk2[p0 + i];
            int pos = atomicAdd(&cur[(pk >> 20) & 127], 1);
            stg[pos] = pk & 0xFFFFFu;
        }
        __syncthreads();
        for (int i = tid; i < cb; i += 256) epk[p0 + i] = stg[i];
    } else {   // statistically never; correctness fallback
        for (int i = tid; i < cb; i += 256) {
            unsigned pk = epk2[p0 + i];
            int pos = atomicAdd(&cur[(pk >> 20) & 127], 1);
            epk[p0 + pos] = pk & 0xFFFFFu;
        }
    }
}

// -------- weight prep, all 3 layers in ONE launch --------
// per layer: blocks 0..25 = B fragments (fp16 hi/lo planes); 26..28 = q/g
__global__ void k_wprep3(
    const float* __restrict__ Wr0, const float* __restrict__ Ws0, const float* __restrict__ Wk0,
    const float* __restrict__ av0, const float* __restrict__ gw0,
    _Float16* __restrict__ Bh0, _Float16* __restrict__ Bl0, float* __restrict__ q0, float* __restrict__ g0,
    const float* __restrict__ Wr1, const float* __restrict__ Ws1, const float* __restrict__ Wk1,
    const float* __restrict__ av1, const float* __restrict__ gw1,
    _Float16* __restrict__ Bh1, _Float16* __restrict__ Bl1, float* __restrict__ q1, float* __restrict__ g1,
    const float* __restrict__ Wr2, const float* __restrict__ Ws2, const float* __restrict__ Wk2,
    const float* __restrict__ av2, const float* __restrict__ gw2,
    _Float16* __restrict__ Bh2, _Float16* __restrict__ Bl2, float* __restrict__ q2, float* __restrict__ g2) {
    int layer = blockIdx.x / (NKS + 3);
    int bx = blockIdx.x % (NKS + 3);
    const float* Wrel  = layer == 0 ? Wr0 : layer == 1 ? Wr1 : Wr2;
    const float* Wself = layer == 0 ? Ws0 : layer == 1 ? Ws1 : Ws2;
    const float* Wskip = layer == 0 ? Wk0 : layer == 1 ? Wk1 : Wk2;
    const float* av    = layer == 0 ? av0 : layer == 1 ? av1 : av2;
    const float* gw    = layer == 0 ? gw0 : layer == 1 ? gw1 : gw2;
    _Float16* Bh = layer == 0 ? Bh0 : layer == 1 ? Bh1 : Bh2;
    _Float16* Bl = layer == 0 ? Bl0 : layer == 1 ? Bl1 : Bl2;
    float* q = layer == 0 ? q0 : layer == 1 ? q1 : q2;
    float* g = layer == 0 ? g0 : layer == 1 ? g1 : g2;

    if (bx < NKS) {
        int t = bx * 256 + threadIdx.x;
        int ks = t >> 8, ct = (t >> 6) & 3, lane = t & 63;
        int col = ct * 16 + (lane & 15);
        int kb = ks * 32 + ((lane >> 4) << 3);
        _Float16* ph = Bh + (size_t)t * 8;
        _Float16* pl = Bl + (size_t)t * 8;
#pragma unroll
        for (int i = 0; i < 8; i++) {
            int k = kb + i;
            float v;
            if (k < 768) v = Wrel[(size_t)k * DD + col];
            else {
                v = Wself[(size_t)(k - 768) * DD + col];
                if (Wskip) v += Wskip[(size_t)(k - 768) * DD + col];
            }
            _Float16 h = (_Float16)v;
            ph[i] = h;
            pl[i] = (_Float16)(v - (float)h);
        }
    } else {
        int t = (bx - NKS) * 256 + threadIdx.x;
        if (t >= RR * DD) return;
        const float* wp = Wrel + (size_t)t * DD;
        float aq = 0.f, ag = 0.f;
#pragma unroll
        for (int e = 0; e < DD; e++) { float w = wp[e]; aq += w * av[e]; ag += w * gw[e]; }
        q[t] = aq; g[t] = ag;
    }
}

// ---------------- fused layer kernel: aggregate -> LDS A-tile -> MFMA ------
// Phase 1: per-edge (ev, ev*gate) gathered in-kernel from the src-indexed EW
// table on the scalar path; Z = in-loop sum of ew.x (exact reference
// semantics). XD=1 (layer 1): h-row recomputed in-register from scalar
// x[src] (no gather). EW double-buffered across layers.
#define AGG_EDGE(ee, wy, hh)                                       \
    switch (ee) {                                                  \
        case 0:  acc[0]  = fmaf(wy, hh, acc[0]);  break;           \
        case 1:  acc[1]  = fmaf(wy, hh, acc[1]);  break;           \
        case 2:  acc[2]  = fmaf(wy, hh, acc[2]);  break;           \
        case 3:  acc[3]  = fmaf(wy, hh, acc[3]);  break;           \
        case 4:  acc[4]  = fmaf(wy, hh, acc[4]);  break;           \
        case 5:  acc[5]  = fmaf(wy, hh, acc[5]);  break;           \
        case 6:  acc[6]  = fmaf(wy, hh, acc[6]);  break;           \
        case 7:  acc[7]  = fmaf(wy, hh, acc[7]);  break;           \
        case 8:  acc[8]  = fmaf(wy, hh, acc[8]);  break;           \
        case 9:  acc[9]  = fmaf(wy, hh, acc[9]);  break;           \
        case 10: acc[10] = fmaf(wy, hh, acc[10]); break;           \
        default: acc[11] = fmaf(wy, hh, acc[11]); break;           \
    }

template<int NB, bool MASKED, int XD>
__device__ __forceinline__ void ebatch(const unsigned* __restrict__ epk,
                                       const float2* __restrict__ EWr,
                                       const _Float16* __restrict__ hin16,
                                       const float* __restrict__ xsrc,
                                       float we_r, float be_r,
                                       int p, int p1, int lane,
                                       float acc[RR], float& zacc) {
    int len = p1 - p;   // uniform; >= 1 when called masked
    unsigned pk[NB];
    float2 ew[NB];
#pragma unroll
    for (int i = 0; i < NB; i++) {
        int ii = MASKED ? (i < len ? i : len - 1) : i;   // clamp: always-valid
        pk[i] = epk[p + ii];
    }
#pragma unroll
    for (int i = 0; i < NB; i++)
        ew[i] = EWr[(size_t)(pk[i] & 0xFFFFu) * RR + ((pk[i] >> 16) & 15u)];
    if (XD) {
        float xs[NB];
#pragma unroll
        for (int i = 0; i < NB; i++) xs[i] = xsrc[pk[i] & 0xFFFFu];
        __builtin_amdgcn_sched_barrier(0);
#pragma unroll
        for (int i = 0; i < NB; i++) {
            int e = __builtin_amdgcn_readfirstlane((int)((pk[i] >> 16) & 15u));
            float hh = fmaf(xs[i], we_r, be_r);
            hh = hh > 0.f ? hh : 0.f;
            float wx = ew[i].x, wy = ew[i].y;
            if (MASKED && i >= 1) {
                bool ok = i < len;
                wx = ok ? wx : 0.f;
                wy = ok ? wy : 0.f;
            }
            zacc += wx;
            AGG_EDGE(e, wy, hh);
        }
    } else {
        _Float16 hr[NB];
#pragma unroll
        for (int i = 0; i < NB; i++)
            hr[i] = hin16[(size_t)(pk[i] & 0xFFFFu) * DD + lane];
        __builtin_amdgcn_sched_barrier(0);
#pragma unroll
        for (int i = 0; i < NB; i++) {
            int e = __builtin_amdgcn_readfirstlane((int)((pk[i] >> 16) & 15u));
            float hh = (float)hr[i];
            float wx = ew[i].x, wy = ew[i].y;
            if (MASKED && i >= 1) {
                bool ok = i < len;
                wx = ok ? wx : 0.f;
                wy = ok ? wy : 0.f;
            }
            zacc += wx;
            AGG_EDGE(e, wy, hh);
        }
    }
}

template<int XD>
__global__ void __launch_bounds__(512, 8)
k_fused(const unsigned* __restrict__ epk, const int* __restrict__ offd,
        const _Float16* __restrict__ hin16,
        const float* __restrict__ xsrc, const float* __restrict__ Wemb,
        const float* __restrict__ bemb,
        const float2* __restrict__ EWr, float2* __restrict__ EWw,
        const _Float16* __restrict__ Bh, const _Float16* __restrict__ Bl,
        const float* __restrict__ bias, float* __restrict__ out,
        _Float16* __restrict__ hout16, int N, int act,
        const float* __restrict__ qn, const float* __restrict__ gn,
        const float* __restrict__ gbn) {
    __shared__ __align__(16) _Float16 At[TROWS * ASTR];   // 26880 B
    __shared__ __align__(16) float Hf[TROWS * 68];        //  4352 B
    __shared__ __align__(16) float qg[2 * RR * 68];       //  6528 B
    __shared__ int offs[TROWS + 1];
    __shared__ int claim;
    int tid = threadIdx.x, lane = tid & 63, w = tid >> 6;
    int nb0 = blockIdx.x * TROWS;
    if (tid == 0) claim = 0;
    if (tid < TROWS + 1) {
        int nn = nb0 + tid;
        offs[tid] = (nn <= N) ? offd[nn] : 0;
    }
    if (EWw) {   // preload next layer's q/g into LDS (stride 68)
        for (int i = tid; i < RR * DD; i += 512) {
            int r = i >> 6, c = i & 63;
            qg[r * 68 + c] = qn[i];
            qg[816 + r * 68 + c] = gn[i];
        }
    }
    float we_r = 0.f, be_r = 0.f;
    if (XD) { we_r = Wemb[lane]; be_r = bemb[lane]; }
    __syncthreads();

    // ---- phase 1: waves claim nodes until the tile is done ----
    for (;;) {
        int t0 = 0;
        if (lane == 0) t0 = atomicAdd(&claim, 1);
        int nl = __builtin_amdgcn_readfirstlane(t0);
        if (nl >= TROWS) break;
        int node = nb0 + nl;
        _Float16* Ar = At + nl * ASTR;
        if (node >= N) {
            for (int k = lane; k < KTOT; k += 64) Ar[k] = (_Float16)0.f;
            continue;
        }
        int p0 = __builtin_amdgcn_readfirstlane(offs[nl]);
        int p1 = __builtin_amdgcn_readfirstlane(offs[nl + 1]);

        float acc[RR];
#pragma unroll
        for (int r = 0; r < RR; r++) acc[r] = 0.f;
        float zacc = 0.f;
        int p = p0;
        while (p + 16 <= p1) {
            ebatch<16, false, XD>(epk, EWr, hin16, xsrc, we_r, be_r, p, p1, lane, acc, zacc);
            p += 16;
        }
        int rem = p1 - p;
        if (rem > 8)      ebatch<16, true, XD>(epk, EWr, hin16, xsrc, we_r, be_r, p, p1, lane, acc, zacc);
        else if (rem > 0) ebatch<8, true, XD>(epk, EWr, hin16, xsrc, we_r, be_r, p, p1, lane, acc, zacc);

        float inv = 1.f / (zacc + 1e-16f);
#pragma unroll
        for (int r = 0; r < RR; r++) Ar[r * DD + lane] = (_Float16)(acc[r] * inv);
        if (XD) {   // self/skip col recomputed from x[node]
            float h0v = fmaf(xsrc[node], we_r, be_r);
            h0v = h0v > 0.f ? h0v : 0.f;
            Ar[768 + lane] = (_Float16)h0v;
        } else {
            Ar[768 + lane] = hin16[(size_t)node * DD + lane];
        }
    }
    __syncthreads();

    // ---- phase 2: waves 0-3 compute col-tiles (16 cols each) ----
    if (w < 4) {
        const half8v* Bh8 = (const half8v*)Bh;
        const half8v* Bl8 = (const half8v*)Bl;
        const _Float16* abase = At + (lane & 15) * ASTR + ((lane >> 4) << 3);
        f32x4 acc0 = {0.f, 0.f, 0.f, 0.f};
#pragma unroll 4
        for (int ks = 0; ks < NKS; ++ks) {
            half8v ah = *(const half8v*)(abase + ks * 32);
            size_t bb = (size_t)(ks * 4 + w) * 64 + lane;
            half8v bh = Bh8[bb];
            half8v bl = Bl8[bb];
            acc0 = __builtin_amdgcn_mfma_f32_16x16x32_f16(ah, bh, acc0, 0, 0, 0);
            acc0 = __builtin_amdgcn_mfma_f32_16x16x32_f16(ah, bl, acc0, 0, 0, 0);
        }

        // epilogue: D layout col=lane&15, row=(lane>>4)*4+j
        int colb = lane & 15, kg = lane >> 4;
        int c = w * 16 + colb;
        float bv = bias[c];
#pragma unroll
        for (int j = 0; j < 4; j++) {
            int rl = kg * 4 + j;
            int row = nb0 + rl;
            if (row < N) {
                float v = acc0[j] + bv;
                if (act) v = v > 0.f ? v : 0.f;
                if (out) out[(size_t)row * DD + c] = v;
                if (hout16) hout16[(size_t)row * DD + c] = (_Float16)v;
                if (EWw) Hf[rl * 68 + c] = v;
            }
        }
    }

    // ---- EW epilogue: next layer's (ev, ev*gate) from fp32 tile, all-LDS ----
    if (EWw) {
        __syncthreads();
        if (tid < TROWS * RR) {
            int nl = tid / RR, r = tid - nl * RR;
            int node = nb0 + nl;
            if (node < N) {
                const float* hp = Hf + nl * 68;
                const float* qp = qg + r * 68;
                const float* gp = qg + 816 + r * 68;
                float aq = 0.f, ag = 0.f;
#pragma unroll
                for (int c4 = 0; c4 < 16; c4++) {
                    float4 hv = *(const float4*)(hp + c4 * 4);
                    float4 qv = *(const float4*)(qp + c4 * 4);
                    float4 gv = *(const float4*)(gp + c4 * 4);
                    aq += hv.x * qv.x + hv.y * qv.y + hv.z * qv.z + hv.w * qv.w;
                    ag += hv.x * gv.x + hv.y * gv.y + hv.z * gv.z + hv.w * gv.w;
                }
                float sc = aq > 0.f ? aq : 0.01f * aq;
                float ev = expf(sc);
                float gate = 1.f / (1.f + expf(-(ag + gbn[0])));
                EWw[(size_t)node * RR + r] = make_float2(ev, ev * gate);
            }
        }
    }
}

extern "C" void kernel_launch(void* const* d_in, const int* in_sizes, int n_in,
                              void* d_out, int out_size, void* d_ws, size_t ws_size,
                              hipStream_t stream) {
    const float* x    = (const float*)d_in[0];
    const int*   src  = (const int*)d_in[1];
    const int*   dst  = (const int*)d_in[2];
    const int*   etyp = (const int*)d_in[3];
    const float* Wemb = (const float*)d_in[4];
    const float* bemb = (const float*)d_in[5];
    const int N = in_sizes[0];
    const int E = in_sizes[1];
    const int nbuck = (N + 127) >> 7;
    const int nblk2 = (E + EPB2 - 1) / EPB2;

    const float* Wrel[3];  const float* Wself[3]; const float* bb[3];
    const float* gwv[3];   const float* gbv[3];   const float* av[3];
    for (int l = 0; l < 3; l++) {
        int o = 6 + 6 * l;
        Wrel[l]  = (const float*)d_in[o + 0];
        Wself[l] = (const float*)d_in[o + 1];
        bb[l]    = (const float*)d_in[o + 2];
        gwv[l]   = (const float*)d_in[o + 3];
        gbv[l]   = (const float*)d_in[o + 4];
        av[l]    = (const float*)d_in[o + 5];
    }
    const float* Wskip[3] = { nullptr, (const float*)d_in[24], (const float*)d_in[25] };

    // ---- workspace ----
    float* p = (float*)d_ws;
    _Float16* h16A = (_Float16*)p; p += (size_t)N * DD / 2;   // fp16 copy (ping)
    _Float16* h16B = (_Float16*)p; p += (size_t)N * DD / 2;   // fp16 copy (pong)
    float2* EWa = (float2*)p; p += (size_t)N * RR * 2;        // EW ping
    float2* EWb = (float2*)p; p += (size_t)N * RR * 2;        // EW pong
    float* qv3[3]; float* gv3[3]; _Float16* Bh3[3]; _Float16* Bl3[3];
    for (int l = 0; l < 3; l++) {
        qv3[l] = p; p += RR * DD;
        gv3[l] = p; p += RR * DD;
        Bh3[l] = (_Float16*)p; p += NKS * 4 * 64 * 8 / 2;
        Bl3[l] = (_Float16*)p; p += NKS * 4 * 64 * 8 / 2;
    }
    unsigned* epk2 = (unsigned*)p; p += E;
    unsigned* epk  = (unsigned*)p; p += E;
    int* bcnt  = (int*)p; p += 512;
    int* bbase = (int*)p; p += 516;
    int* bcur  = (int*)p; p += 512;
    int* offd  = (int*)p; p += N + 4;

    const int B = 256;

    // weight prep for all 3 layers — ONE launch
    k_wprep3<<<3 * (NKS + 3), B, 0, stream>>>(
        Wrel[0], Wself[0], Wskip[0], av[0], gwv[0], Bh3[0], Bl3[0], qv3[0], gv3[0],
        Wrel[1], Wself[1], Wskip[1], av[1], gwv[1], Bh3[1], Bl3[1], qv3[1], gv3[1],
        Wrel[2], Wself[2], Wskip[2], av[2], gwv[2], Bh3[2], Bl3[2], qv3[2], gv3[2]);

    // coalesced two-level dst-sort (once; reused by all layers)
    hipMemsetAsync(bcnt, 0, 512 * 4, stream);
    k_bh<<<nblk2, 512, 0, stream>>>(dst, bcnt, E, nbuck);
    k_bscan<<<1, 512, 0, stream>>>(bcnt, bbase, bcur, nbuck, E);
    k_bscat<<<nblk2, 512, 0, stream>>>(src, dst, etyp, bcur, epk2, E, nbuck);
    k_b2<<<nbuck, 256, 0, stream>>>(epk2, bbase, epk, offd, N, E);

    // layer 1's EW straight from x
    k_sgw2<<<(N * RR + B - 1) / B, B, 0, stream>>>(x, Wemb, bemb, qv3[0], gv3[0],
                                                   gbv[0], EWa, N);

    const int fblocks = (N + TROWS - 1) / TROWS;

    // layer 1: h0 recomputed from x in-register (no k_h0, no h-gather);
    // out h16B; reads EWa, writes layer-2 EW into EWb
    k_fused<1><<<fblocks, 512, 0, stream>>>(epk, offd, nullptr, x, Wemb, bemb,
                                            EWa, EWb, Bh3[0], Bl3[0], bb[0],
                                            nullptr, h16B, N, 1,
                                            qv3[1], gv3[1], gbv[1]);
    // layer 2: in h16B, out h16A; reads EWb, writes layer-3 EW into EWa
    k_fused<0><<<fblocks, 512, 0, stream>>>(epk, offd, h16B, nullptr, nullptr, nullptr,
                                            EWb, EWa, Bh3[1], Bl3[1], bb[1],
                                            nullptr, h16A, N, 1,
                                            qv3[2], gv3[2], gbv[2]);
    // layer 3: in h16A, out d_out f32, no act, no EW epilogue
    k_fused<0><<<fblocks, 512, 0, stream>>>(epk, offd, h16A, nullptr, nullptr, nullptr,
                                            EWa, nullptr, Bh3[2], Bl3[2], bb[2],
                                            (float*)d_out, nullptr, N, 0,
                                            nullptr, nullptr, nullptr);
}